// Round 27
// baseline (50.846 us; speedup 1.0000x reference)
//
#include <hip/hip_runtime.h>
#include <math.h>

#define BATCH 2
#define NNODE 512
#define DIN   128
#define DOUT  128
#define DE    32
#define NEG   0.2f
#define TIB   4       // i-rows per agg block

typedef __attribute__((ext_vector_type(8))) short bf16x8;
typedef __attribute__((ext_vector_type(4))) float f32x4;

__device__ inline short f2bf(float f) {   // RNE f32 -> bf16 (staging only)
    union { float f; unsigned u; } v; v.f = f;
    unsigned r = v.u + 0x7fffu + ((v.u >> 16) & 1u);
    return (short)(r >> 16);
}

// HW packed conversion: 2 f32 -> 2 bf16 (RNE).
__device__ inline unsigned cvtpk(float lo, float hi) {
    unsigned r;
    asm("v_cvt_pk_bf16_f32 %0, %1, %2" : "=v"(r) : "v"(lo), "v"(hi));
    return r;
}
typedef union { bf16x8 v; unsigned u[4]; } bfu;

// VALU-only 16-lane sum via DPP row-rotate.
template<int CTRL>
__device__ inline float dpp_add(float x) {
    const int y = __builtin_amdgcn_update_dpp(0, __float_as_int(x), CTRL, 0xF, 0xF, false);
    return x + __int_as_float(y);
}
__device__ inline float row16_sum(float x) {
    x = dpp_add<0x128>(x);   // row_ror:8
    x = dpp_add<0x124>(x);   // row_ror:4
    x = dpp_add<0x122>(x);   // row_ror:2
    x = dpp_add<0x121>(x);   // row_ror:1
    return x;
}

// ---------------------------------------------------------------------------
// Kernel 1: x_l = x@W_l + b_l ; x_r = x@W_r + b_r   (4 rows/block)
// ---------------------------------------------------------------------------
__global__ __launch_bounds__(256) void xlr_kernel(
    const float* __restrict__ x,  const float* __restrict__ Wl,
    const float* __restrict__ bl, const float* __restrict__ Wr,
    const float* __restrict__ br, float* __restrict__ xl,
    float* __restrict__ xr)
{
    const int r0 = blockIdx.x * 4;
    const int d  = threadIdx.x & 127;
    const int hv = threadIdx.x >> 7;
    __shared__ float xs[4][DIN];
    for (int idx = threadIdx.x; idx < 4 * DIN; idx += 256)
        xs[idx >> 7][idx & 127] = x[(size_t)r0 * DIN + idx];
    __syncthreads();
    const int ra = 2 * hv, rb = ra + 1;
    float al0 = bl[d], al1 = al0, ar0 = br[d], ar1 = ar0;
    #pragma unroll 4
    for (int k = 0; k < DIN; ++k) {
        const float wl = Wl[k * DOUT + d], wr = Wr[k * DOUT + d];
        const float xa = xs[ra][k], xb = xs[rb][k];
        al0 = fmaf(xa, wl, al0); al1 = fmaf(xb, wl, al1);
        ar0 = fmaf(xa, wr, ar0); ar1 = fmaf(xb, wr, ar1);
    }
    xl[(size_t)(r0 + ra) * DOUT + d] = al0;
    xl[(size_t)(r0 + rb) * DOUT + d] = al1;
    xr[(size_t)(r0 + ra) * DOUT + d] = ar0;
    xr[(size_t)(r0 + rb) * DOUT + d] = ar1;
}

// ---------------------------------------------------------------------------
// Kernel 2 (score): r26 sequential-walk + DEPTH-3 e-prefetch (the one
// variable changed). Each pass's e-load now issues ~3 passes (~900 cy) before
// use, matching HBM/L3 latency (m126). Rotation via named registers (all
// indices compile-time; rule #20). Block = one (b,i) row; 8 passes of 64 j
// walk the row's 64 KB linearly. Per-pass math identical to the verified
// body (MFMA fragment mapping, xl in C-init, cvt_pk, DPP reduce).
// ---------------------------------------------------------------------------
__global__ __launch_bounds__(256, 2) void score_kernel(
    const float* __restrict__ xl, const float* __restrict__ xr,
    const float* __restrict__ e,  const float* __restrict__ We,
    const float* __restrict__ att, float* __restrict__ sc)
{
    const int bi   = blockIdx.x;         // b*NNODE + i
    const int b    = bi >> 9;
    const int t    = threadIdx.x;
    const int wave = t >> 6;
    const int lane = t & 63;
    const int col  = lane & 15;
    const int g    = lane >> 4;

    __shared__ short WeT_s[DOUT][DE];        // 8 KB  [d][k] bf16
    __shared__ float att_s[DOUT];

    for (int idx = t; idx < DE * DOUT; idx += 256) {
        const int k = idx >> 7, d = idx & 127;
        WeT_s[d][k] = f2bf(We[idx]);
    }
    if (t < DOUT) att_s[t] = att[t];
    __syncthreads();

    bf16x8 bf[8];
    float  atv[8], xrv[8];
    #pragma unroll
    for (int dt = 0; dt < 8; ++dt) {
        bf[dt]  = *(const bf16x8*)&WeT_s[dt * 16 + col][g * 8];
        atv[dt] = att_s[dt * 16 + col];
        xrv[dt] = xr[(size_t)bi * DOUT + dt * 16 + col];   // this row's xr (L2)
    }

    // e walk: pass s reads j in [s*64, s*64+64) -> 8 KB contiguous per pass.
    const float* ew = e + ((size_t)bi * NNODE + wave * 16 + col) * DE + g * 8;
    const size_t pstep = 64 * DE;            // floats per pass (8 KB)
    const float* xlb = xl + (size_t)(b * NNODE + wave * 16 + g * 4) * DOUT + col;

    // depth-3 pipeline: pa = pass s, pb = s+1, pc = s+2 (named regs, static)
    f32x4 pa0 = *(const f32x4*)ew;
    f32x4 pa1 = *(const f32x4*)(ew + 4);
    f32x4 pb0 = *(const f32x4*)(ew + pstep);
    f32x4 pb1 = *(const f32x4*)(ew + pstep + 4);
    f32x4 pc0 = *(const f32x4*)(ew + 2 * pstep);
    f32x4 pc1 = *(const f32x4*)(ew + 2 * pstep + 4);

    #pragma unroll
    for (int s = 0; s < 8; ++s) {
        const int spf = (s + 3 < 8) ? s + 3 : 7;         // clamped depth-3
        const float* apn = ew + (size_t)spf * pstep;
        const f32x4 n0 = *(const f32x4*)apn;
        const f32x4 n1 = *(const f32x4*)(apn + 4);

        // xl C-init for this pass's j-strip (32 L2 loads)
        const float* xp = xlb + (size_t)s * 64 * DOUT;
        f32x4 xlv4[8];
        #pragma unroll
        for (int dt = 0; dt < 8; ++dt)
            #pragma unroll
            for (int r = 0; r < 4; ++r)
                xlv4[dt][r] = xp[(size_t)r * DOUT + dt * 16];

        bfu af;
        af.u[0] = cvtpk(pa0[0], pa0[1]); af.u[1] = cvtpk(pa0[2], pa0[3]);
        af.u[2] = cvtpk(pa1[0], pa1[1]); af.u[3] = cvtpk(pa1[2], pa1[3]);

        float part[4] = {0.f, 0.f, 0.f, 0.f};
        #pragma unroll
        for (int dt = 0; dt < 8; ++dt) {                 // MFMA, C-in = xl
            const f32x4 c = __builtin_amdgcn_mfma_f32_16x16x32_bf16(af.v, bf[dt], xlv4[dt], 0, 0, 0);
            #pragma unroll
            for (int r = 0; r < 4; ++r) {
                float p = c[r] + xrv[dt];
                p = fmaxf(p, NEG * p);                   // leaky_relu
                part[r] = fmaf(atv[dt], p, part[r]);
            }
        }
        #pragma unroll
        for (int r = 0; r < 4; ++r) part[r] = row16_sum(part[r]);

        if (col == 0) {
            float4 v; float* vp = (float*)&v;
            #pragma unroll
            for (int r = 0; r < 4; ++r) vp[r] = part[r];
            *(float4*)&sc[(size_t)bi * NNODE + s * 64 + wave * 16 + g * 4] = v;
        }
        pa0 = pb0; pa1 = pb1;                            // rotate pipeline
        pb0 = pc0; pb1 = pc1;
        pc0 = n0;  pc1 = n1;
    }
}

// ---------------------------------------------------------------------------
// Kernel 3 (agg): masking + softmax + aggregation (r13/r14-verified).
// ---------------------------------------------------------------------------
__global__ __launch_bounds__(256) void agg_kernel(
    const float* __restrict__ xl, const float* __restrict__ sc,
    const void* __restrict__ adjv, const void* __restrict__ maskv,
    const float* __restrict__ bias, float* __restrict__ out)
{
    const int bid = blockIdx.x;          // 512 blocks: (b, iT:128, dh:2)
    const int dh  = bid & 1;
    const int iT  = (bid >> 1) & 127;
    const int b   = bid >> 8;
    const int i0  = iT * TIB, d0 = dh * 64;
    const int t    = threadIdx.x;
    const int wave = t >> 6;
    const int lane = t & 63;

    __shared__ float al_s[TIB][NNODE];   // 8 KB
    __shared__ float ps_s[4][TIB][64];   // 4 KB partials
    __shared__ float inv_s[TIB];
    __shared__ int   mflag[2];

    if (t < 2) mflag[t] = 0;
    {   // adj dtype probe (first 16 KB, L2-resident)
        const unsigned* aw = (const unsigned*)adjv;
        unsigned sawF = 0, sawG = 0;
        #pragma unroll
        for (int k = 0; k < 16; ++k) {
            const unsigned w = aw[t + 256 * k];
            sawF |= (w == 0x3f800000u);
            sawG |= (w > 1u);
        }
        if (sawF) atomicOr(&mflag[0], 1);
        if (sawG) atomicOr(&mflag[1], 1);
    }
    for (int idx = t; idx < TIB * NNODE; idx += 256) {
        const int r = idx >> 9, jj = idx & 511;
        al_s[r][jj] = sc[(size_t)(b * NNODE + i0 + r) * NNODE + jj];
    }
    __syncthreads();
    const int byteMode = (!mflag[0] && mflag[1]) ? 1 : 0;

    // mask + softmax: wave w owns row w; adj row read is coalesced
    {
        const int ig = i0 + wave;
        const unsigned char* aB = (const unsigned char*)adjv + (size_t)(b * NNODE + ig) * NNODE;
        const unsigned*      aW = (const unsigned*)adjv + (size_t)(b * NNODE + ig) * NNODE;
        float v[8], m = -1e30f;
        #pragma unroll
        for (int k = 0; k < 8; ++k) {
            const int j = lane + 64 * k;
            const bool conn = (j == ig) ||
                (byteMode ? (aB[j] != 0) : (aW[j] != 0));
            v[k] = conn ? al_s[wave][j] : -1e30f;
            m = fmaxf(m, v[k]);
        }
        #pragma unroll
        for (int off = 32; off; off >>= 1) m = fmaxf(m, __shfl_xor(m, off, 64));
        float s = 0.f;
        #pragma unroll
        for (int k = 0; k < 8; ++k) {
            const float ex = __expf(v[k] - m);   // masked -> exp(-huge) = 0
            al_s[wave][lane + 64 * k] = ex;
            s += ex;
        }
        #pragma unroll
        for (int off = 32; off; off >>= 1) s += __shfl_xor(s, off, 64);
        if (lane == 0) inv_s[wave] = 1.f / s;
    }
    __syncthreads();

    // j-partitioned aggregation: wave w covers j in [128w, 128w+128)
    const int d = d0 + lane;
    const float* xb = xl + (size_t)b * NNODE * DOUT + d;
    float ac[TIB] = {0.f, 0.f, 0.f, 0.f};
    const int jlo = wave * 128;
    for (int j4 = jlo; j4 < jlo + 128; j4 += 4) {
        const f32x4 a0 = *(const f32x4*)&al_s[0][j4];
        const f32x4 a1 = *(const f32x4*)&al_s[1][j4];
        const f32x4 a2 = *(const f32x4*)&al_s[2][j4];
        const f32x4 a3 = *(const f32x4*)&al_s[3][j4];
        #pragma unroll
        for (int k = 0; k < 4; ++k) {
            const float xv = xb[(size_t)(j4 + k) * DOUT];
            ac[0] = fmaf(a0[k], xv, ac[0]);
            ac[1] = fmaf(a1[k], xv, ac[1]);
            ac[2] = fmaf(a2[k], xv, ac[2]);
            ac[3] = fmaf(a3[k], xv, ac[3]);
        }
    }
    #pragma unroll
    for (int r = 0; r < TIB; ++r) ps_s[wave][r][lane] = ac[r];
    __syncthreads();

    // combine: wave r finishes row r
    {
        const int r = wave;
        float val = (ps_s[0][r][lane] + ps_s[1][r][lane]) +
                    (ps_s[2][r][lane] + ps_s[3][r][lane]);
        const int mi = b * NNODE + i0 + r;
        const bool mv = byteMode ? (((const unsigned char*)maskv)[mi] != 0)
                                 : (((const unsigned*)maskv)[mi] != 0);
        val = val * inv_s[r] + bias[d];
        if (!mv) val = 0.f;
        val = val / (1.f + __expf(-val));    // silu
        out[(size_t)mi * DOUT + d] = val;
    }
}

// ---------------------------------------------------------------------------
extern "C" void kernel_launch(void* const* d_in, const int* in_sizes, int n_in,
                              void* d_out, int out_size, void* d_ws, size_t ws_size,
                              hipStream_t stream)
{
    const float* x    = (const float*)d_in[0];
    const void*  adj  = d_in[1];
    const float* e    = (const float*)d_in[2];
    const void*  mask = d_in[3];
    const float* Wl   = (const float*)d_in[4];
    const float* bl   = (const float*)d_in[5];
    const float* Wr   = (const float*)d_in[6];
    const float* br   = (const float*)d_in[7];
    const float* We   = (const float*)d_in[8];
    const float* att  = (const float*)d_in[9];
    const float* bias = (const float*)d_in[10];
    float*       out  = (float*)d_out;

    float* xl = (float*)d_ws;                              // 512 KB
    float* xr = xl + (size_t)BATCH * NNODE * DOUT;         // 512 KB
    float* sc = xr + (size_t)BATCH * NNODE * DOUT;         // 2 MB scores

    xlr_kernel<<<(BATCH * NNODE) / 4, 256, 0, stream>>>(x, Wl, bl, Wr, br, xl, xr);
    score_kernel<<<BATCH * NNODE, 256, 0, stream>>>(xl, xr, e, We, att, sc);
    agg_kernel<<<BATCH * (NNODE / TIB) * 2, 256, 0, stream>>>(
        xl, sc, adj, mask, bias, out);
}

// Round 28
// 49.828 us; speedup vs baseline: 1.0204x; 1.0204x over previous
//
#include <hip/hip_runtime.h>
#include <math.h>

#define BATCH 2
#define NNODE 512
#define DIN   128
#define DOUT  128
#define DE    32
#define NEG   0.2f
#define TI    8       // i-rows per score block (1024 blocks, prologue amortized)
#define TJ    64      // j-cols per score block (4 waves x 16)
#define TIB   4       // i-rows per agg block

typedef __attribute__((ext_vector_type(8))) short bf16x8;
typedef __attribute__((ext_vector_type(4))) float f32x4;

__device__ inline short f2bf(float f) {   // RNE f32 -> bf16 (staging only)
    union { float f; unsigned u; } v; v.f = f;
    unsigned r = v.u + 0x7fffu + ((v.u >> 16) & 1u);
    return (short)(r >> 16);
}

// HW packed conversion: 2 f32 -> 2 bf16 in one instruction (RNE). Guide T12.
__device__ inline unsigned cvtpk(float lo, float hi) {
    unsigned r;
    asm("v_cvt_pk_bf16_f32 %0, %1, %2" : "=v"(r) : "v"(lo), "v"(hi));
    return r;
}
typedef union { bf16x8 v; unsigned u[4]; } bfu;

// VALU-only 16-lane sum via DPP row-rotate (no DS ops, no lgkm waits).
template<int CTRL>
__device__ inline float dpp_add(float x) {
    const int y = __builtin_amdgcn_update_dpp(0, __float_as_int(x), CTRL, 0xF, 0xF, false);
    return x + __int_as_float(y);
}
__device__ inline float row16_sum(float x) {
    x = dpp_add<0x128>(x);   // row_ror:8
    x = dpp_add<0x124>(x);   // row_ror:4
    x = dpp_add<0x122>(x);   // row_ror:2
    x = dpp_add<0x121>(x);   // row_ror:1
    return x;
}

// ---------------------------------------------------------------------------
// Kernel 1: x_l = x@W_l + b_l ; x_r = x@W_r + b_r   (4 rows/block)
// ---------------------------------------------------------------------------
__global__ __launch_bounds__(256) void xlr_kernel(
    const float* __restrict__ x,  const float* __restrict__ Wl,
    const float* __restrict__ bl, const float* __restrict__ Wr,
    const float* __restrict__ br, float* __restrict__ xl,
    float* __restrict__ xr)
{
    const int r0 = blockIdx.x * 4;
    const int d  = threadIdx.x & 127;
    const int hv = threadIdx.x >> 7;
    __shared__ float xs[4][DIN];
    for (int idx = threadIdx.x; idx < 4 * DIN; idx += 256)
        xs[idx >> 7][idx & 127] = x[(size_t)r0 * DIN + idx];
    __syncthreads();
    const int ra = 2 * hv, rb = ra + 1;
    float al0 = bl[d], al1 = al0, ar0 = br[d], ar1 = ar0;
    #pragma unroll 4
    for (int k = 0; k < DIN; ++k) {
        const float wl = Wl[k * DOUT + d], wr = Wr[k * DOUT + d];
        const float xa = xs[ra][k], xb = xs[rb][k];
        al0 = fmaf(xa, wl, al0); al1 = fmaf(xb, wl, al1);
        ar0 = fmaf(xa, wr, ar0); ar1 = fmaf(xb, wr, ar1);
    }
    xl[(size_t)(r0 + ra) * DOUT + d] = al0;
    xl[(size_t)(r0 + rb) * DOUT + d] = al1;
    xr[(size_t)(r0 + ra) * DOUT + d] = ar0;
    xr[(size_t)(r0 + rb) * DOUT + d] = ar1;
}

// ---------------------------------------------------------------------------
// Kernel 2 (score): r14-exact (verified session optimum, 50.2-50.4 us total):
// TI=8, i-unroll x2 at __launch_bounds__(256,2), adj-free (masking in agg),
// xl in MFMA C-init, cvt_pk asm for f32->bf16, DPP reduce, depth-1 pair
// prefetch. Ten structural alternatives (deeper prefetch, LDS pipelines,
// burst staging, occupancy/ILP/pattern changes) all measured null-to-worse.
// ---------------------------------------------------------------------------
__global__ __launch_bounds__(256, 2) void score_kernel(
    const float* __restrict__ xl, const float* __restrict__ xr,
    const float* __restrict__ e,  const float* __restrict__ We,
    const float* __restrict__ att, float* __restrict__ sc)
{
    const int bid = blockIdx.x;          // 1024 blocks: (b, iT:64, jT:8)
    const int jT  = bid & 7;
    const int iT  = (bid >> 3) & 63;
    const int b   = bid >> 9;
    const int i0  = iT * TI, j0 = jT * TJ;
    const int t    = threadIdx.x;
    const int wave = t >> 6;
    const int lane = t & 63;
    const int col  = lane & 15;
    const int g    = lane >> 4;

    __shared__ short WeT_s[DOUT][DE];        // 8 KB  [d][k] bf16
    __shared__ float xr_s[TI][DOUT];         // 4 KB
    __shared__ float att_s[DOUT];

    for (int idx = t; idx < DE * DOUT; idx += 256) {
        const int k = idx >> 7, d = idx & 127;
        WeT_s[d][k] = f2bf(We[idx]);
    }
    for (int idx = t; idx < TI * DOUT; idx += 256) {
        const int ii = idx >> 7, d = idx & 127;
        xr_s[ii][d] = xr[(size_t)(b * NNODE + i0 + ii) * DOUT + d];
    }
    if (t < DOUT) att_s[t] = att[t];

    // xl -> MFMA C-init registers (i-invariant per lane)
    f32x4 xlv4[8];
    {
        const float* xb = xl + (size_t)(b * NNODE + j0 + wave * 16 + g * 4) * DOUT + col;
        #pragma unroll
        for (int dt = 0; dt < 8; ++dt)
            #pragma unroll
            for (int r = 0; r < 4; ++r)
                xlv4[dt][r] = xb[(size_t)r * DOUT + dt * 16];
    }
    __syncthreads();

    bf16x8 bf[8];
    float  atv[8];
    #pragma unroll
    for (int dt = 0; dt < 8; ++dt) {
        bf[dt]  = *(const bf16x8*)&WeT_s[dt * 16 + col][g * 8];
        atv[dt] = att_s[dt * 16 + col];
    }

    const int jw = j0 + wave * 16;           // this wave's 16-j tile
    const float* ebase = e + ((size_t)(b * NNODE + i0) * NNODE + jw + col) * DE + g * 8;
    const size_t estep = (size_t)NNODE * DE; // per-i stride

    f32x4 p0a = *(const f32x4*)ebase;
    f32x4 p0b = *(const f32x4*)(ebase + 4);
    f32x4 p1a = *(const f32x4*)(ebase + estep);
    f32x4 p1b = *(const f32x4*)(ebase + estep + 4);

    for (int i = 0; i < TI; i += 2) {
        // branchless clamped prefetch of rows i+2, i+3
        const int ipf = (i + 2 < TI) ? i + 2 : i;
        const float* apn = ebase + (size_t)ipf * estep;
        const f32x4 n0a = *(const f32x4*)apn;
        const f32x4 n0b = *(const f32x4*)(apn + 4);
        const f32x4 n1a = *(const f32x4*)(apn + estep);
        const f32x4 n1b = *(const f32x4*)(apn + estep + 4);

        bfu af0, af1;                         // packed bf16 via HW cvt (1 op / 2 vals)
        af0.u[0] = cvtpk(p0a[0], p0a[1]); af0.u[1] = cvtpk(p0a[2], p0a[3]);
        af0.u[2] = cvtpk(p0b[0], p0b[1]); af0.u[3] = cvtpk(p0b[2], p0b[3]);
        af1.u[0] = cvtpk(p1a[0], p1a[1]); af1.u[1] = cvtpk(p1a[2], p1a[3]);
        af1.u[2] = cvtpk(p1b[0], p1b[1]); af1.u[3] = cvtpk(p1b[2], p1b[3]);

        float part0[4] = {0.f, 0.f, 0.f, 0.f};
        float part1[4] = {0.f, 0.f, 0.f, 0.f};
        #pragma unroll
        for (int dt = 0; dt < 8; ++dt) {     // two independent MFMA chains
            const f32x4 c0 = __builtin_amdgcn_mfma_f32_16x16x32_bf16(af0.v, bf[dt], xlv4[dt], 0, 0, 0);
            const f32x4 c1 = __builtin_amdgcn_mfma_f32_16x16x32_bf16(af1.v, bf[dt], xlv4[dt], 0, 0, 0);
            const float xrv0 = xr_s[i][dt * 16 + col];
            const float xrv1 = xr_s[i + 1][dt * 16 + col];
            #pragma unroll
            for (int r = 0; r < 4; ++r) {
                float p = c0[r] + xrv0;
                p = fmaxf(p, NEG * p);
                part0[r] = fmaf(atv[dt], p, part0[r]);
                float q = c1[r] + xrv1;
                q = fmaxf(q, NEG * q);
                part1[r] = fmaf(atv[dt], q, part1[r]);
            }
        }
        #pragma unroll
        for (int r = 0; r < 4; ++r) {
            part0[r] = row16_sum(part0[r]);
            part1[r] = row16_sum(part1[r]);
        }
        if (col == 0) {
            const int jb = jw + g * 4;
            float4 v0, v1;
            float* vp0 = (float*)&v0;
            float* vp1 = (float*)&v1;
            #pragma unroll
            for (int r = 0; r < 4; ++r) { vp0[r] = part0[r]; vp1[r] = part1[r]; }
            *(float4*)&sc[(size_t)(b * NNODE + i0 + i) * NNODE + jb]     = v0;
            *(float4*)&sc[(size_t)(b * NNODE + i0 + i + 1) * NNODE + jb] = v1;
        }
        p0a = n0a; p0b = n0b; p1a = n1a; p1b = n1b;
    }
}

// ---------------------------------------------------------------------------
// Kernel 3 (agg): masking + softmax + aggregation (r13/r14-verified). Wave w
// owns row w: coalesced adj row read, mask+self-loop in max pass, softmax,
// then j-partitioned aggregation across waves, LDS partial combine.
// ---------------------------------------------------------------------------
__global__ __launch_bounds__(256) void agg_kernel(
    const float* __restrict__ xl, const float* __restrict__ sc,
    const void* __restrict__ adjv, const void* __restrict__ maskv,
    const float* __restrict__ bias, float* __restrict__ out)
{
    const int bid = blockIdx.x;          // 512 blocks: (b, iT:128, dh:2)
    const int dh  = bid & 1;
    const int iT  = (bid >> 1) & 127;
    const int b   = bid >> 8;
    const int i0  = iT * TIB, d0 = dh * 64;
    const int t    = threadIdx.x;
    const int wave = t >> 6;
    const int lane = t & 63;

    __shared__ float al_s[TIB][NNODE];   // 8 KB
    __shared__ float ps_s[4][TIB][64];   // 4 KB partials
    __shared__ float inv_s[TIB];
    __shared__ int   mflag[2];

    if (t < 2) mflag[t] = 0;
    {   // adj dtype probe (first 16 KB, L2-resident)
        const unsigned* aw = (const unsigned*)adjv;
        unsigned sawF = 0, sawG = 0;
        #pragma unroll
        for (int k = 0; k < 16; ++k) {
            const unsigned w = aw[t + 256 * k];
            sawF |= (w == 0x3f800000u);
            sawG |= (w > 1u);
        }
        if (sawF) atomicOr(&mflag[0], 1);
        if (sawG) atomicOr(&mflag[1], 1);
    }
    for (int idx = t; idx < TIB * NNODE; idx += 256) {
        const int r = idx >> 9, jj = idx & 511;
        al_s[r][jj] = sc[(size_t)(b * NNODE + i0 + r) * NNODE + jj];
    }
    __syncthreads();
    const int byteMode = (!mflag[0] && mflag[1]) ? 1 : 0;

    // mask + softmax: wave w owns row w; adj row read is coalesced
    {
        const int ig = i0 + wave;
        const unsigned char* aB = (const unsigned char*)adjv + (size_t)(b * NNODE + ig) * NNODE;
        const unsigned*      aW = (const unsigned*)adjv + (size_t)(b * NNODE + ig) * NNODE;
        float v[8], m = -1e30f;
        #pragma unroll
        for (int k = 0; k < 8; ++k) {
            const int j = lane + 64 * k;
            const bool conn = (j == ig) ||
                (byteMode ? (aB[j] != 0) : (aW[j] != 0));
            v[k] = conn ? al_s[wave][j] : -1e30f;
            m = fmaxf(m, v[k]);
        }
        #pragma unroll
        for (int off = 32; off; off >>= 1) m = fmaxf(m, __shfl_xor(m, off, 64));
        float s = 0.f;
        #pragma unroll
        for (int k = 0; k < 8; ++k) {
            const float ex = __expf(v[k] - m);   // masked -> exp(-huge) = 0
            al_s[wave][lane + 64 * k] = ex;
            s += ex;
        }
        #pragma unroll
        for (int off = 32; off; off >>= 1) s += __shfl_xor(s, off, 64);
        if (lane == 0) inv_s[wave] = 1.f / s;
    }
    __syncthreads();

    // j-partitioned aggregation: wave w covers j in [128w, 128w+128)
    const int d = d0 + lane;
    const float* xb = xl + (size_t)b * NNODE * DOUT + d;
    float ac[TIB] = {0.f, 0.f, 0.f, 0.f};
    const int jlo = wave * 128;
    for (int j4 = jlo; j4 < jlo + 128; j4 += 4) {
        const f32x4 a0 = *(const f32x4*)&al_s[0][j4];
        const f32x4 a1 = *(const f32x4*)&al_s[1][j4];
        const f32x4 a2 = *(const f32x4*)&al_s[2][j4];
        const f32x4 a3 = *(const f32x4*)&al_s[3][j4];
        #pragma unroll
        for (int k = 0; k < 4; ++k) {
            const float xv = xb[(size_t)(j4 + k) * DOUT];
            ac[0] = fmaf(a0[k], xv, ac[0]);
            ac[1] = fmaf(a1[k], xv, ac[1]);
            ac[2] = fmaf(a2[k], xv, ac[2]);
            ac[3] = fmaf(a3[k], xv, ac[3]);
        }
    }
    #pragma unroll
    for (int r = 0; r < TIB; ++r) ps_s[wave][r][lane] = ac[r];
    __syncthreads();

    // combine: wave r finishes row r
    {
        const int r = wave;
        float val = (ps_s[0][r][lane] + ps_s[1][r][lane]) +
                    (ps_s[2][r][lane] + ps_s[3][r][lane]);
        const int mi = b * NNODE + i0 + r;
        const bool mv = byteMode ? (((const unsigned char*)maskv)[mi] != 0)
                                 : (((const unsigned*)maskv)[mi] != 0);
        val = val * inv_s[r] + bias[d];
        if (!mv) val = 0.f;
        val = val / (1.f + __expf(-val));    // silu
        out[(size_t)mi * DOUT + d] = val;
    }
}

// ---------------------------------------------------------------------------
extern "C" void kernel_launch(void* const* d_in, const int* in_sizes, int n_in,
                              void* d_out, int out_size, void* d_ws, size_t ws_size,
                              hipStream_t stream)
{
    const float* x    = (const float*)d_in[0];
    const void*  adj  = d_in[1];
    const float* e    = (const float*)d_in[2];
    const void*  mask = d_in[3];
    const float* Wl   = (const float*)d_in[4];
    const float* bl   = (const float*)d_in[5];
    const float* Wr   = (const float*)d_in[6];
    const float* br   = (const float*)d_in[7];
    const float* We   = (const float*)d_in[8];
    const float* att  = (const float*)d_in[9];
    const float* bias = (const float*)d_in[10];
    float*       out  = (float*)d_out;

    float* xl = (float*)d_ws;                              // 512 KB
    float* xr = xl + (size_t)BATCH * NNODE * DOUT;         // 512 KB
    float* sc = xr + (size_t)BATCH * NNODE * DOUT;         // 2 MB scores

    xlr_kernel<<<(BATCH * NNODE) / 4, 256, 0, stream>>>(x, Wl, bl, Wr, br, xl, xr);
    score_kernel<<<BATCH * (NNODE / TI) * (NNODE / TJ), 256, 0, stream>>>(
        xl, xr, e, We, att, sc);
    agg_kernel<<<BATCH * (NNODE / TIB) * 2, 256, 0, stream>>>(
        xl, sc, adj, mask, bias, out);
}